// Round 3
// baseline (645.881 us; speedup 1.0000x reference)
//
#include <hip/hip_runtime.h>
#include <math.h>
#include <limits.h>

#define S_N 65536
#define D_N 512
#define B_N 64

typedef __attribute__((ext_vector_type(8))) short short8;
typedef __attribute__((ext_vector_type(4))) float f32x4;

// ---------------- workspace layout (float indices) ----------------
#define SIMS_F      (B_N*S_N/2)
#define OFF_SIMS    0
#define OFF_AEXT    (OFF_SIMS + SIMS_F)         // ushort[96*512] bf16: rows 0..63 norm(nc), 64..95 ec_w^T
#define AEXT_F      (96*512/2)
#define OFF_NORMS   (OFF_AEXT + AEXT_F)
#define OFF_CONF    (OFF_NORMS + S_N)
#define OFF_FLAGS   (OFF_CONF + S_N)            // int
#define OFF_LIST    (OFF_FLAGS + S_N)           // int[256]
#define OFF_MASKED  (OFF_LIST + 256)
#define OFF_ERSC    (OFF_MASKED + S_N)
#define OFF_SLOTAGE (OFF_ERSC + S_N)
#define OFF_STORES  (OFF_SLOTAGE + S_N)         // 64
#define OFF_MAXSIM  (OFF_STORES + 64)           // 64 u32 mono
#define OFF_TI      (OFF_MAXSIM + 64)           // 192 int
#define OFF_TV      (OFF_TI + 192)              // 192
#define OFF_APPLY   (OFF_TV + 192)              // 192 int
#define OFF_WIN     (OFF_APPLY + 192)           // 192 int
#define OFF_T4      (OFF_WIN + 192)             // 256 chunks * 8 (4 val + 4 idx)
#define OFF_DNC0    (OFF_T4 + 2048)             // 3*512
#define OFF_DRIFT0  (OFF_DNC0 + 1536)           // 512
#define OFF_DOCAND  (OFF_DRIFT0 + 512)          // 192*512
#define OFF_HNC     (OFF_DOCAND + 98304)        // mlp2 nc-half partials 2*64*2*256
#define OFF_HG      (OFF_HNC + 65536)           // mlp2 gathered partials 2*192*2*256
#define OFF_SCAL    (OFF_HG + 196608)

// ---------------- output layout (floats) ----------------
#define OUT_MEM 0
#define OUT_AT  (S_N*D_N)
#define OUT_ER  (OUT_AT + S_N)
#define OUT_SS  (OUT_ER + S_N)
#define OUT_NOV (OUT_SS + 64)
#define OUT_RC  (OUT_NOV + 64)

struct __align__(8) Scal {
  unsigned long long victim_pack;
  unsigned long long masked_pack;
  unsigned long long slotage_pack;
  int cnt_active;
  int cond_cnt;
  unsigned age_max_t;
  float nov_mean;
  float changed_sum;
  int do_erase;
  int should_store;
  int write_idx;
  int victim_idx;
  int list_cnt;
  int done;
};

__device__ __forceinline__ float sigmoidf_(float x){ return 1.0f/(1.0f+expf(-x)); }
__device__ __forceinline__ unsigned f2mono(float f){
  unsigned u = __float_as_uint(f);
  return (u & 0x80000000u) ? ~u : (u | 0x80000000u);
}
__device__ __forceinline__ float mono2f(unsigned m){
  unsigned u = (m & 0x80000000u) ? (m & 0x7FFFFFFFu) : ~m;
  return __uint_as_float(u);
}
__device__ __forceinline__ unsigned long long packvi(float v, int i){
  return (((unsigned long long)f2mono(v)) << 32) | (unsigned long long)(0xFFFFFFFFu - (unsigned)i);
}
__device__ __forceinline__ bool betterVI(float v, int i, float v2, int i2){
  return (v > v2) || (v == v2 && i < i2);
}
__device__ __forceinline__ unsigned bf16r(float f){
  unsigned u = __float_as_uint(f);
  return (u + 0x7fffu + ((u>>16)&1u)) >> 16;
}
__device__ __forceinline__ float bf2f(unsigned short h){
  return __uint_as_float(((unsigned)h)<<16);
}
__device__ __forceinline__ void touch_row(int row, float* ws){
  int* flags = (int*)(ws + OFF_FLAGS);
  if (atomicExch(&flags[row], 1) == 0){
    Scal* sc = (Scal*)(ws + OFF_SCAL);
    int i = atomicAdd(&sc->list_cnt, 1);
    ((int*)(ws + OFF_LIST))[i] = row;
  }
}
// patched victim values (used redundantly by several blocks; cheap)
__device__ __forceinline__ void victim_vals(float stepf,
    const float* el_w, const float* el_b, const float* eg_w, const float* eg_b,
    const float* ec_b, float* er_v, float* slot_v, float* conf0){
  float x = (stepf + 99999.0f) / 1000.0f;
  float lp = 0.0f, c0 = 0.0f;
  #pragma unroll
  for (int j=0;j<32;j++){
    lp += fmaxf(x*el_w[j] + el_b[j], 0.0f) * eg_w[j];
    c0 += sigmoidf_(ec_b[j]) * eg_w[32 + j];
  }
  *conf0 = c0;
  *er_v = sigmoidf_(lp + c0 + eg_b[0]);
  *slot_v = stepf + 99999.0f;
}

// ================= K1: init + AEXT + agemax + at-copy + flags + full mlp1 =================
__global__ __launch_bounds__(256) void k_init(const float* __restrict__ nc,
    const float* __restrict__ qr, const float* __restrict__ at_in,
    const float* __restrict__ ec_w, const int* __restrict__ step_p,
    const float* __restrict__ sr_w1, const float* __restrict__ sr_b1,
    const float* __restrict__ sr_g,  const float* __restrict__ sr_beta,
    const float* __restrict__ sr_w2, const float* __restrict__ sr_b2,
    const float* __restrict__ sn_w,  const float* __restrict__ sn_b,
    const float* __restrict__ sg_w,  const float* __restrict__ sg_b,
    float* __restrict__ ws, float* __restrict__ out){
  int blk = blockIdx.x, t = threadIdx.x;
  Scal* sc = (Scal*)(ws + OFF_SCAL);
  unsigned short* aB = (unsigned short*)(ws + OFF_AEXT);
  if (blk == 0){
    if (t == 0){
      sc->victim_pack = 0ULL; sc->masked_pack = 0ULL; sc->slotage_pack = 0ULL;
      sc->cnt_active = 0; sc->cond_cnt = 0; sc->age_max_t = 0u;
      sc->nov_mean = 0.0f; sc->changed_sum = 0.0f;
      sc->do_erase = 0; sc->should_store = 0; sc->write_idx = 0; sc->victim_idx = 0;
      sc->list_cnt = 0; sc->done = 0;
    }
    if (t < 64) ((unsigned*)(ws + OFF_MAXSIM))[t] = 0u;
  } else if (blk <= 64){
    int b = blk - 1;
    __shared__ float red[256];
    float x0 = nc[b*512 + t], x1 = nc[b*512 + 256 + t];
    red[t] = x0*x0 + x1*x1;
    __syncthreads();
    for (int o=128;o>0;o>>=1){ if (t<o) red[t]+=red[t+o]; __syncthreads(); }
    float inv = 1.0f / fmaxf(sqrtf(red[0]), 1e-12f);
    aB[b*512 + t]       = (unsigned short)bf16r(x0*inv);
    aB[b*512 + 256 + t] = (unsigned short)bf16r(x1*inv);
  } else if (blk <= 96){
    int j = blk - 65;
    for (int d=t; d<512; d+=256) aB[(64+j)*512 + d] = (unsigned short)bf16r(ec_w[d*32 + j]);
  } else if (blk <= 160){
    int part = blk - 97;
    float stepf = (float)step_p[0];
    float lmax = -1e30f;
    for (int s = part*1024 + t; s < (part+1)*1024; s += 256)
      lmax = fmaxf(lmax, fmaxf(stepf - at_in[s], 0.0f));
    __shared__ float red[256];
    red[t]=lmax; __syncthreads();
    for (int o=128;o>0;o>>=1){ if (t<o) red[t]=fmaxf(red[t],red[t+o]); __syncthreads(); }
    if (t==0) atomicMax(&sc->age_max_t, f2mono(red[0]));
  } else if (blk <= 224){
    int part = blk - 161;
    for (int s = part*1024 + t; s < (part+1)*1024; s += 256)
      out[OUT_AT + s] = at_in[s];
  } else if (blk <= 288){
    int part = blk - 225;
    int* flags = (int*)(ws + OFF_FLAGS);
    for (int s = part*1024 + t; s < (part+1)*1024; s += 256) flags[s] = 0;
  } else {
    // ---- full store-gate MLP, one block per b ----
    int b = blk - 289;
    __shared__ float comb[1024];
    __shared__ float hbuf[256];
    __shared__ float red[256];
    comb[t]       = nc[b*512 + t];
    comb[256 + t] = nc[b*512 + 256 + t];
    comb[512 + t] = qr[b*512 + t];
    comb[768 + t] = qr[b*512 + 256 + t];
    __syncthreads();
    float h0=0.f,h1=0.f,h2=0.f,h3=0.f;
    const float* w = sr_w1 + t;
    for (int i=0;i<1024;i+=4){
      h0 = fmaf(comb[i],   w[(i  )*256], h0);
      h1 = fmaf(comb[i+1], w[(i+1)*256], h1);
      h2 = fmaf(comb[i+2], w[(i+2)*256], h2);
      h3 = fmaf(comb[i+3], w[(i+3)*256], h3);
    }
    float h = ((h0+h1)+(h2+h3)) + sr_b1[t];
    red[t] = h; __syncthreads();
    for (int o=128;o>0;o>>=1){ if (t<o) red[t]+=red[t+o]; __syncthreads(); }
    float mean = red[0] / 256.0f;
    __syncthreads();
    float dx = h - mean;
    red[t] = dx*dx; __syncthreads();
    for (int o=128;o>0;o>>=1){ if (t<o) red[t]+=red[t+o]; __syncthreads(); }
    float var = red[0] / 256.0f;
    __syncthreads();
    float hn = dx / sqrtf(var + 1e-5f) * sr_g[t] + sr_beta[t];
    hbuf[t] = fmaxf(hn, 0.0f);
    __syncthreads();
    float val = 0.0f;
    if (t < 128){
      float r0=0.f, r1=0.f;
      const float* w2 = sr_w2 + t;
      for (int j=0;j<256;j+=2){
        r0 = fmaf(hbuf[j],   w2[(j  )*128], r0);
        r1 = fmaf(hbuf[j+1], w2[(j+1)*128], r1);
      }
      float r = fmaxf(r0+r1+sr_b2[t], 0.0f);
      float n0=0.f,n1=0.f,n2=0.f,n3=0.f;
      const float* wn = sn_w + t;
      for (int d=0; d<512; d+=4){
        n0 = fmaf(comb[d],   wn[(d  )*128], n0);
        n1 = fmaf(comb[d+1], wn[(d+1)*128], n1);
        n2 = fmaf(comb[d+2], wn[(d+2)*128], n2);
        n3 = fmaf(comb[d+3], wn[(d+3)*128], n3);
      }
      float nf = sigmoidf_(((n0+n1)+(n2+n3)) + sn_b[t]);
      val = (r + nf) * sg_w[t];
    }
    red[t] = val; __syncthreads();
    for (int o=128;o>0;o>>=1){ if (t<o) red[t]+=red[t+o]; __syncthreads(); }
    if (t == 0){
      float ssc = sigmoidf_(red[0] + sg_b[0]);
      out[OUT_SS + b] = ssc;
      ws[OFF_STORES + b] = ssc;
    }
  }
}

// ================= K2: phase1 — barrier-free fused copy/norm/sims/conf MFMA =================
// block = 64 s-rows. lane(wv,quad,l15) owns mem row s0+wv*16+l15, cols kc*32+quad*8.
__global__ __launch_bounds__(256,4) void k_phase1(const float* __restrict__ mem,
    const float* __restrict__ ec_b, const float* __restrict__ eg_w,
    float* __restrict__ ws, float* __restrict__ out){
  int t = threadIdx.x;
  int s0 = blockIdx.x * 64;
  int lane = t & 63, wv = t >> 6;
  int quad = lane >> 4, l15 = lane & 15;
  int row = wv*16 + l15;
  const float* rp = mem + (size_t)(s0 + row)*512 + quad*8;
  float*       op = out + OUT_MEM + (size_t)(s0 + row)*512 + quad*8;
  const unsigned short* aB = (const unsigned short*)(ws + OFF_AEXT);
  Scal* sc = (Scal*)(ws + OFF_SCAL);
  f32x4 acc[6];
  #pragma unroll
  for (int r=0;r<6;r++) acc[r] = (f32x4){0.f,0.f,0.f,0.f};
  float ssq = 0.f;
  #pragma unroll 4
  for (int kc=0;kc<16;kc++){
    float4 a0 = *(const float4*)(rp + kc*32);
    float4 a1 = *(const float4*)(rp + kc*32 + 4);
    *(float4*)(op + kc*32)     = a0;
    *(float4*)(op + kc*32 + 4) = a1;
    ssq = fmaf(a0.x,a0.x,ssq); ssq = fmaf(a0.y,a0.y,ssq);
    ssq = fmaf(a0.z,a0.z,ssq); ssq = fmaf(a0.w,a0.w,ssq);
    ssq = fmaf(a1.x,a1.x,ssq); ssq = fmaf(a1.y,a1.y,ssq);
    ssq = fmaf(a1.z,a1.z,ssq); ssq = fmaf(a1.w,a1.w,ssq);
    union { short8 s8; unsigned u[4]; } bf;
    bf.u[0] = (bf16r(a0.y)<<16) | bf16r(a0.x);
    bf.u[1] = (bf16r(a0.w)<<16) | bf16r(a0.z);
    bf.u[2] = (bf16r(a1.y)<<16) | bf16r(a1.x);
    bf.u[3] = (bf16r(a1.w)<<16) | bf16r(a1.z);
    int kb = kc*32 + quad*8;
    #pragma unroll
    for (int rt=0;rt<6;rt++){
      short8 af = *(const short8*)&aB[(rt*16 + l15)*512 + kb];
      acc[rt] = __builtin_amdgcn_mfma_f32_16x16x32_bf16(af, bf.s8, acc[rt], 0,0,0);
    }
  }
  // row norm: reduce over quads
  ssq += __shfl_xor(ssq, 16);
  ssq += __shfl_xor(ssq, 32);
  float nrm = sqrtf(ssq);
  float inv = 1.0f / fmaxf(nrm, 1e-12f);
  if (quad == 0) ws[OFF_NORMS + s0 + row] = nrm;
  __shared__ int cnt4[4];
  unsigned long long bal = __ballot(quad==0 && nrm > 0.5f);
  if (lane == 0) cnt4[wv] = (int)__popcll(bal);
  // sims epilogue: D col=l15 (scol = our own row), D row = quad*4+r
  unsigned short* simsb = (unsigned short*)(ws + OFF_SIMS);
  unsigned* gmsu = (unsigned*)(ws + OFF_MAXSIM);
  #pragma unroll
  for (int rt=0;rt<4;rt++){
    #pragma unroll
    for (int r=0;r<4;r++){
      int a = rt*16 + quad*4 + r;
      float sim = acc[rt][r] * inv;
      simsb[(size_t)a*S_N + s0 + row] = (unsigned short)bf16r(sim);
      float m = sim;
      m = fmaxf(m, __shfl_xor(m, 1));
      m = fmaxf(m, __shfl_xor(m, 2));
      m = fmaxf(m, __shfl_xor(m, 4));
      m = fmaxf(m, __shfl_xor(m, 8));
      if (l15 == 0){
        unsigned mm = f2mono(m);
        if (mm > gmsu[a]) atomicMax(&gmsu[a], mm);
      }
    }
  }
  // conf: rows 64..95 of D
  float cpart = 0.f;
  #pragma unroll
  for (int rt=4;rt<6;rt++){
    #pragma unroll
    for (int r=0;r<4;r++){
      int j = (rt-4)*16 + quad*4 + r;
      cpart += sigmoidf_(acc[rt][r] + ec_b[j]) * eg_w[32+j];
    }
  }
  cpart += __shfl_xor(cpart, 16);
  cpart += __shfl_xor(cpart, 32);
  if (quad == 0) ws[OFF_CONF + s0 + row] = cpart;
  __syncthreads();
  if (t == 0) atomicAdd(&sc->cnt_active, cnt4[0]+cnt4[1]+cnt4[2]+cnt4[3]);
}

// ================= K3: scan(+novelty) + top4-partials + erase-main =================
__global__ __launch_bounds__(256) void k_scan(const float* __restrict__ at_in,
    const int* __restrict__ step_p,
    const float* __restrict__ el_w, const float* __restrict__ el_b,
    const float* __restrict__ eg_w, const float* __restrict__ eg_b,
    float* __restrict__ ws, float* __restrict__ out){
  int blk = blockIdx.x, t = threadIdx.x;
  Scal* sc = (Scal*)(ws + OFF_SCAL);
  float stepf = (float)step_p[0];
  if (blk < 512){
    // redundant per-block nov_mean from global maxsim
    __shared__ float nred[64];
    const unsigned* gms = (const unsigned*)(ws + OFF_MAXSIM);
    if (t < 64){
      float nv = (1.0f - mono2f(gms[t])) * 0.5f;
      nred[t] = nv;
      if (blk == 0) out[OUT_NOV + t] = nv;
    }
    __syncthreads();
    if (t < 32) nred[t] += nred[t+32];
    __syncthreads();
    if (t < 16) nred[t] += nred[t+16];
    __syncthreads();
    if (t < 8)  nred[t] += nred[t+8];
    __syncthreads();
    if (t < 4)  nred[t] += nred[t+4];
    __syncthreads();
    float nov_mean = (nred[0]+nred[1]+nred[2]+nred[3]) / 64.0f;
    if (blk == 0 && t == 0) sc->nov_mean = nov_mean;
    float thr = 1.0f - nov_mean;
    float agemax = mono2f(sc->age_max_t);
    const unsigned* simsu = (const unsigned*)(ws + OFF_SIMS);
    const float* norms = ws + OFF_NORMS;
    int gid = blk*256 + t;
    int gstride = 512*256;
    int cnt = 0;
    for (int idx = gid; idx < B_N*S_N/2; idx += gstride){
      unsigned u = simsu[idx];
      int s = (idx*2) & (S_N-1);
      float v0 = __uint_as_float(u<<16);
      float v1 = __uint_as_float(u & 0xffff0000u);
      if (v0 > thr && norms[s]   > 0.5f) cnt++;
      if (v1 > thr && norms[s+1] > 0.5f) cnt++;
    }
    unsigned long long best = 0ULL;
    for (int s = gid; s < S_N; s += gstride){
      float age = fmaxf(stepf - at_in[s], 0.0f);
      float es = age/(agemax + 1e-6f) + (1.0f - sigmoidf_(norms[s]));
      unsigned long long pk = packvi(es, s);
      if (pk > best) best = pk;
    }
    __shared__ int redc[256];
    __shared__ unsigned long long redp[256];
    redc[t] = cnt; redp[t] = best;
    __syncthreads();
    for (int o=128;o>0;o>>=1){
      if (t<o){ redc[t]+=redc[t+o]; if (redp[t+o] > redp[t]) redp[t]=redp[t+o]; }
      __syncthreads();
    }
    if (t == 0){
      atomicAdd(&sc->cond_cnt, redc[0]);
      atomicMax(&sc->victim_pack, redp[0]);
    }
  } else if (blk < 768){
    // ---- top4 partial: idx = blk-512; b = idx>>2, chunk = idx&3 ----
    int idx = blk - 512;
    int b = idx >> 2, ch = idx & 3;
    const unsigned short* simrow = (const unsigned short*)(ws + OFF_SIMS) + (size_t)b*S_N + ch*16384;
    float v[4] = {-1e30f,-1e30f,-1e30f,-1e30f};
    int ix[4] = {INT_MAX,INT_MAX,INT_MAX,INT_MAX};
    for (int s = t; s < 16384; s += 256){
      int gs = ch*16384 + s;
      float val = bf2f(simrow[s]);
      if (betterVI(val, gs, v[3], ix[3])){
        if (betterVI(val, gs, v[1], ix[1])){
          if (betterVI(val, gs, v[0], ix[0])){
            v[3]=v[2];ix[3]=ix[2]; v[2]=v[1];ix[2]=ix[1]; v[1]=v[0];ix[1]=ix[0]; v[0]=val;ix[0]=gs;
          } else { v[3]=v[2];ix[3]=ix[2]; v[2]=v[1];ix[2]=ix[1]; v[1]=val;ix[1]=gs; }
        } else {
          if (betterVI(val, gs, v[2], ix[2])){ v[3]=v[2];ix[3]=ix[2]; v[2]=val;ix[2]=gs; }
          else { v[3]=val; ix[3]=gs; }
        }
      }
    }
    __shared__ float sv[256*4];
    __shared__ int   si[256*4];
    for (int r=0;r<4;r++){ sv[t*4+r]=v[r]; si[t*4+r]=ix[r]; }
    for (int off=128; off>0; off>>=1){
      __syncthreads();
      if (t < off){
        float av[4], bv[4], ov[4]; int ai[4], bi[4], oi[4];
        for (int r=0;r<4;r++){ av[r]=sv[t*4+r]; ai[r]=si[t*4+r]; bv[r]=sv[(t+off)*4+r]; bi[r]=si[(t+off)*4+r]; }
        int ap=0, bp=0;
        for (int r=0;r<4;r++){
          bool takeA = (bp>=4) || (ap<4 && betterVI(av[ap],ai[ap],bv[bp],bi[bp]));
          if (takeA){ ov[r]=av[ap]; oi[r]=ai[ap]; ap++; }
          else      { ov[r]=bv[bp]; oi[r]=bi[bp]; bp++; }
        }
        for (int r=0;r<4;r++){ sv[t*4+r]=ov[r]; si[t*4+r]=oi[r]; }
      }
    }
    __syncthreads();
    if (t == 0){
      for (int r=0;r<4;r++){
        ws[OFF_T4 + idx*8 + r] = sv[r];
        ((int*)ws)[OFF_T4 + idx*8 + 4 + r] = si[r];
      }
    }
  } else {
    // ---- erase-main (original at; victim patched later) ----
    int q = blk - 768;
    float egb = eg_b[0];
    for (int s = q*1024 + t; s < (q+1)*1024; s += 256){
      float a = at_in[s];
      float x = (stepf - a) / 1000.0f;
      float lp = 0.0f;
      #pragma unroll
      for (int j=0;j<32;j++) lp += fmaxf(x*el_w[j] + el_b[j], 0.0f) * eg_w[j];
      float er = sigmoidf_(lp + ws[OFF_CONF + s] + egb);
      float sa = stepf - a;
      bool recent = (a >= 0.0f) && (sa < 3.0f);
      ws[OFF_ERSC + s] = er;
      ws[OFF_MASKED + s] = recent ? 0.0f : er;
      ws[OFF_SLOTAGE + s] = sa;
    }
  }
}

// ================= K4: victim patch + top3 merge + erase argmax =================
__global__ __launch_bounds__(256) void k_victop(const int* __restrict__ step_p,
    const float* __restrict__ el_w, const float* __restrict__ el_b,
    const float* __restrict__ eg_w, const float* __restrict__ eg_b,
    const float* __restrict__ ec_b,
    float* __restrict__ ws, float* __restrict__ out){
  int blk = blockIdx.x, t = threadIdx.x;
  Scal* sc = (Scal*)(ws + OFF_SCAL);
  float stepf = (float)step_p[0];
  int de = ((float)sc->cnt_active / 65536.0f > 0.85f) ? 1 : 0;
  int victim = (int)(0xFFFFFFFFu - (unsigned)(sc->victim_pack & 0xFFFFFFFFULL));
  if (blk == 0){
    if (t == 0){ sc->do_erase = de; sc->victim_idx = victim; }
    if (de){
      for (int d=t; d<512; d+=256) out[OUT_MEM + (size_t)victim*512 + d] = 0.0f;
      if (t == 0){
        float er_v, slot_v, c0;
        victim_vals(stepf, el_w, el_b, eg_w, eg_b, ec_b, &er_v, &slot_v, &c0);
        out[OUT_AT + victim] = -99999.0f;
        ws[OFF_CONF + victim] = c0;
        ws[OFF_ERSC + victim] = er_v;
        ws[OFF_MASKED + victim] = er_v;
        ws[OFF_SLOTAGE + victim] = slot_v;
        touch_row(victim, ws);
      }
    }
  } else if (blk <= 64){
    if (t == 0){
      int b = blk - 1;
      float cv[17]; int ci[17]; int n = 0;
      for (int ch=0; ch<4; ch++){
        int idx = b*4 + ch;
        for (int r=0;r<4;r++){
          float v = ws[OFF_T4 + idx*8 + r];
          int ii = ((const int*)ws)[OFF_T4 + idx*8 + 4 + r];
          if (de && ii == victim) continue;
          cv[n] = v; ci[n] = ii; n++;
        }
      }
      if (de){ cv[n] = 0.0f; ci[n] = victim; n++; }
      for (int k=0;k<3;k++){
        int bi = 0;
        for (int j=1;j<n;j++) if (betterVI(cv[j],ci[j],cv[bi],ci[bi])) bi = j;
        ws[OFF_TV + b*3 + k] = cv[bi];
        ((int*)(ws + OFF_TI))[b*3 + k] = ci[bi];
        cv[bi] = -1e30f; ci[bi] = INT_MAX;
      }
    }
  } else {
    int q = blk - 65;   // 64 blocks
    float er_v = 0.f, slot_v = 0.f, c0;
    if (de) victim_vals(stepf, el_w, el_b, eg_w, eg_b, ec_b, &er_v, &slot_v, &c0);
    unsigned long long bm = 0ULL, bs = 0ULL;
    for (int s = q*1024 + t; s < (q+1)*1024; s += 256){
      float msk = ws[OFF_MASKED + s];
      float sa  = ws[OFF_SLOTAGE + s];
      if (de && s == victim){ msk = er_v; sa = slot_v; }
      unsigned long long pm = packvi(msk, s); if (pm > bm) bm = pm;
      unsigned long long ps = packvi(sa,  s); if (ps > bs) bs = ps;
    }
    __shared__ unsigned long long rm[256], rs[256];
    rm[t]=bm; rs[t]=bs; __syncthreads();
    for (int o=128;o>0;o>>=1){
      if (t<o){ if (rm[t+o]>rm[t]) rm[t]=rm[t+o]; if (rs[t+o]>rs[t]) rs[t]=rs[t+o]; }
      __syncthreads();
    }
    if (t == 0){
      atomicMax(&sc->masked_pack, rm[0]);
      atomicMax(&sc->slotage_pack, rs[0]);
    }
  }
}

// ================= K5: mlp2 hidden partials, k-split x4 =================
__global__ __launch_bounds__(256) void k_mlp2(const float* __restrict__ nc,
    const float* __restrict__ dd_w1, const float* __restrict__ ds_w1,
    float* __restrict__ ws, float* __restrict__ out){
  int blk = blockIdx.x, t = threadIdx.x;
  int b = blk >> 2, ks = blk & 3;
  __shared__ float ch[3*256];
  if (ks < 2){
    ch[t] = nc[b*512 + ks*256 + t];
    __syncthreads();
    float hd = 0.f, hs = 0.f;
    const float* wd = dd_w1 + (ks*256)*256 + t;
    const float* wq = ds_w1 + (ks*256)*256 + t;
    for (int i=0;i<256;i++){
      float c = ch[i];
      hd = fmaf(c, wd[i*256], hd);
      hs = fmaf(c, wq[i*256], hs);
    }
    float* H = ws + OFF_HNC + ((ks*64 + b)*2)*256;
    H[t] = hd; H[256 + t] = hs;
  } else {
    int ks2 = ks - 2;
    const int* tip = (const int*)(ws + OFF_TI);
    int r0 = tip[b*3], r1 = tip[b*3+1], r2 = tip[b*3+2];
    ch[t]       = out[OUT_MEM + (size_t)r0*512 + ks2*256 + t];
    ch[256 + t] = out[OUT_MEM + (size_t)r1*512 + ks2*256 + t];
    ch[512 + t] = out[OUT_MEM + (size_t)r2*512 + ks2*256 + t];
    __syncthreads();
    float hd0=0,hd1=0,hd2=0,hs0=0,hs1=0,hs2=0;
    const float* wd = dd_w1 + (512 + ks2*256)*256 + t;
    const float* wq = ds_w1 + (512 + ks2*256)*256 + t;
    for (int i=0;i<256;i++){
      float w0 = wd[i*256], w1 = wq[i*256];
      float c0 = ch[i], c1 = ch[256+i], c2 = ch[512+i];
      hd0=fmaf(c0,w0,hd0); hd1=fmaf(c1,w0,hd1); hd2=fmaf(c2,w0,hd2);
      hs0=fmaf(c0,w1,hs0); hs1=fmaf(c1,w1,hs1); hs2=fmaf(c2,w1,hs2);
    }
    float* H = ws + OFF_HG;
    int p0 = b*3;
    H[((ks2*192 + p0+0)*2+0)*256 + t] = hd0;
    H[((ks2*192 + p0+1)*2+0)*256 + t] = hd1;
    H[((ks2*192 + p0+2)*2+0)*256 + t] = hd2;
    H[((ks2*192 + p0+0)*2+1)*256 + t] = hs0;
    H[((ks2*192 + p0+1)*2+1)*256 + t] = hs1;
    H[((ks2*192 + p0+2)*2+1)*256 + t] = hs2;
  }
}

// ================= K6: pairfin =================
__global__ __launch_bounds__(256) void k_pairfin(const float* __restrict__ nc,
    const float* __restrict__ dd_b1, const float* __restrict__ dd_w2, const float* __restrict__ dd_b2,
    const float* __restrict__ ds_b1, const float* __restrict__ ds_w2, const float* __restrict__ ds_b2,
    float* __restrict__ ws, float* __restrict__ out){
  int p = blockIdx.x, t = threadIdx.x;
  int b = p / 3, k = p - 3*b;
  const int* tip = (const int*)(ws + OFF_TI);
  int row = tip[p];
  float hd = ws[OFF_HNC + ((0*64+b)*2+0)*256 + t] + ws[OFF_HNC + ((1*64+b)*2+0)*256 + t]
           + ws[OFF_HG + ((0*192+p)*2+0)*256 + t] + ws[OFF_HG + ((1*192+p)*2+0)*256 + t] + dd_b1[t];
  float hs = ws[OFF_HNC + ((0*64+b)*2+1)*256 + t] + ws[OFF_HNC + ((1*64+b)*2+1)*256 + t]
           + ws[OFF_HG + ((0*192+p)*2+1)*256 + t] + ws[OFF_HG + ((1*192+p)*2+1)*256 + t] + ds_b1[t];
  __shared__ float red[256];
  __shared__ float bc[2];
  red[t] = fmaxf(hd, 0.f) * dd_w2[t];
  __syncthreads();
  for (int o=128;o>0;o>>=1){ if (t<o) red[t]+=red[t+o]; __syncthreads(); }
  if (t == 0) bc[0] = red[0] + dd_b2[0];
  __syncthreads();
  red[t] = fmaxf(hs, 0.f) * ds_w2[t];
  __syncthreads();
  for (int o=128;o>0;o>>=1){ if (t<o) red[t]+=red[t+o]; __syncthreads(); }
  if (t == 0) bc[1] = red[0] + ds_b2[0];
  __syncthreads();
  float prob  = sigmoidf_(bc[0]);
  float stren = sigmoidf_(bc[1]);
  float tvv = ws[OFF_TV + p];
  int ap = (tvv > 0.7f && tvv < 0.99f && prob > 0.5f) ? 1 : 0;
  if (t == 0) ((int*)(ws + OFF_APPLY))[p] = ap;
  for (int d=t; d<512; d+=256){
    float n = nc[b*512 + d];
    float g = out[OUT_MEM + (size_t)row*512 + d];
    float avg = 0.5f*(n + g);
    ws[OFF_DOCAND + p*512 + d] = (1.0f - stren)*g + stren*avg;
    if (b == 0) ws[OFF_DNC0 + k*512 + d] = (1.0f - stren)*n + stren*avg;
  }
}

// ================= K7: decide + scatter-winner resolution + drift0 =================
__global__ __launch_bounds__(256) void k_decide(const float* __restrict__ nc, float* __restrict__ ws){
  int t = threadIdx.x;
  Scal* sc = (Scal*)(ws + OFF_SCAL);
  __shared__ int stip[192], sap[192], seff[192];
  __shared__ float red[64];
  if (t < 192){ stip[t] = ((int*)(ws+OFF_TI))[t]; sap[t] = ((int*)(ws+OFF_APPLY))[t]; }
  if (t < 64) red[t] = ws[OFF_STORES + t];
  __syncthreads();
  if (t < 32) red[t] += red[t+32];
  __syncthreads();
  if (t < 16) red[t] += red[t+16];
  __syncthreads();
  if (t < 8)  red[t] += red[t+8];
  __syncthreads();
  if (t == 0){
    float store_mean = (red[0]+red[1]+red[2]+red[3]+red[4]+red[5]+red[6]+red[7]) / 64.0f;
    int cnt = sc->cnt_active;
    float capacity = (float)cnt / 65536.0f;
    float dyn_thr;
    if (capacity < 0.3f) dyn_thr = 0.08f;
    else if (capacity < 0.6f) dyn_thr = 0.08f + (capacity - 0.3f)*0.733f;
    else dyn_thr = 0.3f + (capacity - 0.6f);
    dyn_thr = fminf(fmaxf(dyn_thr, 0.0f), 0.7f);
    float topk_thr = (capacity < 0.3f) ? 0.1f : ((capacity < 0.6f) ? 0.2f : 0.4f);
    float raw_thr  = (capacity < 0.3f) ? 0.3f : 0.5f;
    int base_store = store_mean > raw_thr;
    int novelty_ok = sc->nov_mean > dyn_thr;
    int cmax = cnt > 1 ? cnt : 1;
    float perc = (cnt > 0) ? ((float)sc->cond_cnt) / (float)(64 * cmax) : 1.0f;
    int topk_ok = perc > topk_thr;
    int de = sc->do_erase;
    int ss = base_store && novelty_ok && topk_ok;
    if (de && !novelty_ok) ss = 0;
    float mmax = mono2f((unsigned)(sc->masked_pack >> 32));
    int marg = (int)(0xFFFFFFFFu - (unsigned)(sc->masked_pack  & 0xFFFFFFFFULL));
    int sarg = (int)(0xFFFFFFFFu - (unsigned)(sc->slotage_pack & 0xFFFFFFFFULL));
    sc->should_store = ss;
    sc->write_idx = de ? sc->victim_idx : ((mmax > 0.0f) ? marg : sarg);
  }
  // winner resolution: within k, max-b wins; across k, max-k applied wins; non-applied winner = no-op
  if (t < 192){
    int k = t % 3, b = t / 3, row = stip[t];
    int bmax = -1;
    for (int bp=0;bp<64;bp++) if (stip[bp*3+k] == row) bmax = bp;
    seff[t] = (b == bmax && sap[t]) ? 1 : 0;
  }
  __syncthreads();
  if (t < 192){
    int k = t % 3, row = stip[t];
    int winv = seff[t];
    if (winv){
      for (int pp=0;pp<192;pp++)
        if (seff[pp] && stip[pp] == row && (pp % 3) > k){ winv = 0; break; }
    }
    ((int*)(ws+OFF_WIN))[t] = winv;
  }
  __syncthreads();
  for (int d=t; d<512; d+=256){
    float v = nc[d];               // b = 0 row
    if (sap[0]) v = ws[OFF_DNC0 + 0*512 + d];
    if (sap[1]) v = ws[OFF_DNC0 + 1*512 + d];
    if (sap[2]) v = ws[OFF_DNC0 + 2*512 + d];
    ws[OFF_DRIFT0 + d] = v;
  }
}

// ================= K8: ER output + winner scatters + store write =================
__global__ __launch_bounds__(256) void k_final(const int* __restrict__ step_p,
                                               float* __restrict__ ws, float* __restrict__ out){
  int blk = blockIdx.x, t = threadIdx.x;
  Scal* sc = (Scal*)(ws + OFF_SCAL);
  int ss = sc->should_store, de = sc->do_erase;
  if (blk < 64){
    float mmax = mono2f((unsigned)(sc->masked_pack >> 32));
    bool usemask = ss && !de;
    for (int s = blk*1024 + t; s < (blk+1)*1024; s += 256){
      float v;
      if (usemask) v = (mmax <= 0.0f) ? ws[OFF_SLOTAGE + s] : ws[OFF_MASKED + s];
      else v = ws[OFF_ERSC + s];
      out[OUT_ER + s] = v;
    }
  } else if (blk < 256){
    int p = blk - 64;
    if (!((const int*)(ws+OFF_WIN))[p]) return;
    int row = ((const int*)(ws+OFF_TI))[p];
    if (ss && row == sc->write_idx) return;   // store overwrites later anyway
    if (t == 0) touch_row(row, ws);
    for (int d=t; d<512; d+=256)
      out[OUT_MEM + (size_t)row*512 + d] = ws[OFF_DOCAND + p*512 + d];
  } else {
    if (!ss) return;
    int wi = sc->write_idx;
    for (int d=t; d<512; d+=256) out[OUT_MEM + (size_t)wi*512 + d] = ws[OFF_DRIFT0 + d];
    if (t == 0){
      out[OUT_AT + wi] = (float)step_p[0];
      touch_row(wi, ws);
    }
  }
}

// ================= K9: diff over touched rows + rc via completion counter =================
__global__ __launch_bounds__(256) void k_diff(const float* __restrict__ mem,
                                              float* __restrict__ ws, float* __restrict__ out){
  int t = threadIdx.x;
  Scal* sc = (Scal*)(ws + OFF_SCAL);
  int cnt = sc->list_cnt;
  const int* list = (const int*)(ws + OFF_LIST);
  float lsum = 0.0f;
  for (int i = blockIdx.x; i < cnt; i += gridDim.x){
    int row = list[i];
    float part = 0.0f;
    for (int d=t; d<512; d+=256)
      part += fabsf(out[OUT_MEM + (size_t)row*512 + d] - mem[(size_t)row*512 + d]);
    lsum += part;
  }
  __shared__ float red[256];
  red[t] = lsum; __syncthreads();
  for (int o=128;o>0;o>>=1){ if (t<o) red[t]+=red[t+o]; __syncthreads(); }
  if (t == 0){
    if (red[0] != 0.0f) atomicAdd(&sc->changed_sum, red[0]);
    __threadfence();
    int d = atomicAdd(&sc->done, 1);
    if (d == (int)gridDim.x - 1){
      float cs = atomicAdd(&sc->changed_sum, 0.0f);
      out[OUT_RC] = cs / 33554432.0f;   // / (S*D)
    }
  }
}

// ================= host =================
extern "C" void kernel_launch(void* const* d_in, const int* in_sizes, int n_in,
                              void* d_out, int out_size, void* d_ws, size_t ws_size,
                              hipStream_t stream) {
  const float* nc    = (const float*)d_in[0];
  const float* qr    = (const float*)d_in[1];
  const float* mem   = (const float*)d_in[2];
  const float* at    = (const float*)d_in[3];
  const int*   step  = (const int*)  d_in[4];
  const float* sr_w1 = (const float*)d_in[5];
  const float* sr_b1 = (const float*)d_in[6];
  const float* sr_g  = (const float*)d_in[7];
  const float* sr_be = (const float*)d_in[8];
  const float* sr_w2 = (const float*)d_in[9];
  const float* sr_b2 = (const float*)d_in[10];
  const float* sn_w  = (const float*)d_in[11];
  const float* sn_b  = (const float*)d_in[12];
  const float* sg_w  = (const float*)d_in[13];
  const float* sg_b  = (const float*)d_in[14];
  const float* el_w  = (const float*)d_in[15];
  const float* el_b  = (const float*)d_in[16];
  const float* ec_w  = (const float*)d_in[17];
  const float* ec_b  = (const float*)d_in[18];
  const float* eg_w  = (const float*)d_in[19];
  const float* eg_b  = (const float*)d_in[20];
  const float* dd_w1 = (const float*)d_in[21];
  const float* dd_b1 = (const float*)d_in[22];
  const float* dd_w2 = (const float*)d_in[23];
  const float* dd_b2 = (const float*)d_in[24];
  const float* ds_w1 = (const float*)d_in[25];
  const float* ds_b1 = (const float*)d_in[26];
  const float* ds_w2 = (const float*)d_in[27];
  const float* ds_b2 = (const float*)d_in[28];
  float* out = (float*)d_out;
  float* ws  = (float*)d_ws;

  k_init   <<<dim3(353),  dim3(256), 0, stream>>>(nc, qr, at, ec_w, step,
                sr_w1, sr_b1, sr_g, sr_be, sr_w2, sr_b2, sn_w, sn_b, sg_w, sg_b, ws, out);
  k_phase1 <<<dim3(1024), dim3(256), 0, stream>>>(mem, ec_b, eg_w, ws, out);
  k_scan   <<<dim3(832),  dim3(256), 0, stream>>>(at, step, el_w, el_b, eg_w, eg_b, ws, out);
  k_victop <<<dim3(129),  dim3(256), 0, stream>>>(step, el_w, el_b, eg_w, eg_b, ec_b, ws, out);
  k_mlp2   <<<dim3(256),  dim3(256), 0, stream>>>(nc, dd_w1, ds_w1, ws, out);
  k_pairfin<<<dim3(192),  dim3(256), 0, stream>>>(nc, dd_b1, dd_w2, dd_b2,
                                                  ds_b1, ds_w2, ds_b2, ws, out);
  k_decide <<<dim3(1),    dim3(256), 0, stream>>>(nc, ws);
  k_final  <<<dim3(257),  dim3(256), 0, stream>>>(step, ws, out);
  k_diff   <<<dim3(64),   dim3(256), 0, stream>>>(mem, ws, out);
}